// Round 1
// baseline (661.397 us; speedup 1.0000x reference)
//
#include <hip/hip_runtime.h>
#include <stdint.h>

#define NB 2
#define CH 384
#define NH 8
#define CPH 48
#define IMG 128
#define HW 16384

typedef float f32x4 __attribute__((ext_vector_type(4)));
typedef short bf16x8 __attribute__((ext_vector_type(8)));
typedef short short4v __attribute__((ext_vector_type(4)));

__device__ inline unsigned short f2bf(float f){
    unsigned u = __builtin_bit_cast(unsigned, f);
    u += 0x7FFFu + ((u >> 16) & 1u);
    return (unsigned short)(u >> 16);
}
__device__ inline float bf2f(unsigned short h){
    unsigned u = ((unsigned)h) << 16;
    return __builtin_bit_cast(float, u);
}

// ---------------------------------------------------------------------------
// Kernel 1: fused dwconv(q), dwconv(k) -> bf16 hi/lo LDS tiles -> MFMA Gram
// grid (32 bands, 8 heads, 2 batch), block 256. Band = 4 image rows.
// Outputs: Sg[b][h][48][48] (atomicAdd), ssqg[b][h][2][48] (atomicAdd)
// ---------------------------------------------------------------------------
__global__ __launch_bounds__(256, 2) void k_gram(
    const float* __restrict__ qf, const float* __restrict__ kf,
    const float* __restrict__ wq, const float* __restrict__ wk,
    float* __restrict__ Sg, float* __restrict__ ssqg)
{
    __shared__ union {
        unsigned short tiles[4][CPH][136];   // qh, ql, kh, kl ; pad 136 vs 128
        float sred[4 * CPH * CPH];
    } sm;

    const int t = threadIdx.x;
    const int band = blockIdx.x, h = blockIdx.y, b = blockIdx.z;
    const int y0 = band * 4;
    const int wid = t >> 6, lane = t & 63, quad = lane >> 4, l15 = lane & 15;
    const int px0 = wid * 32;

    // conv assignment: threads 0..191: (qk, channel, x-half)
    const int slot = t % 96;
    const int half = t / 96;        // valid for t<192
    const int qk = slot / 48, c = slot % 48;
    const int x0 = half * 64;
    const float* plane = nullptr;
    float w9[9];
    if (t < 192) {
        int gc = h * CPH + c;
        plane = (qk == 0 ? qf : kf) + (size_t)(b * CH + gc) * HW;
        const float* wp = (qk == 0 ? wq : wk) + gc * 9;
#pragma unroll
        for (int i = 0; i < 9; ++i) w9[i] = wp[i];
    }
    float ssqacc = 0.f;

    f32x4 acc[3][3];
#pragma unroll
    for (int i = 0; i < 3; ++i)
#pragma unroll
        for (int j = 0; j < 3; ++j) acc[i][j] = (f32x4){0.f, 0.f, 0.f, 0.f};

    for (int yi = 0; yi < 4; ++yi) {
        const int y = y0 + yi;
        if (t < 192) {
            float lft[3]; float4 c4[3];
            const float* rp[3]; bool rv[3];
#pragma unroll
            for (int dy = 0; dy < 3; ++dy) {
                int yy = y + dy - 1;
                rv[dy] = (yy >= 0 && yy < IMG);
                rp[dy] = plane + yy * IMG;
                lft[dy] = (rv[dy] && x0 > 0) ? rp[dy][x0 - 1] : 0.f;
                c4[dy] = rv[dy] ? *(const float4*)(rp[dy] + x0) : make_float4(0, 0, 0, 0);
            }
#pragma unroll
            for (int j = 0; j < 16; ++j) {
                const int xb = x0 + 4 * j;
                float4 n4[3];
#pragma unroll
                for (int dy = 0; dy < 3; ++dy) {
                    if (j < 15)
                        n4[dy] = rv[dy] ? *(const float4*)(rp[dy] + xb + 4) : make_float4(0, 0, 0, 0);
                    else {
                        float tl = (rv[dy] && (x0 + 64) < IMG) ? rp[dy][x0 + 64] : 0.f;
                        n4[dy] = make_float4(tl, 0, 0, 0);
                    }
                }
                float o0 = 0, o1 = 0, o2 = 0, o3 = 0;
#pragma unroll
                for (int dy = 0; dy < 3; ++dy) {
                    float a0 = w9[dy * 3], a1 = w9[dy * 3 + 1], a2 = w9[dy * 3 + 2];
                    o0 += a0 * lft[dy]  + a1 * c4[dy].x + a2 * c4[dy].y;
                    o1 += a0 * c4[dy].x + a1 * c4[dy].y + a2 * c4[dy].z;
                    o2 += a0 * c4[dy].y + a1 * c4[dy].z + a2 * c4[dy].w;
                    o3 += a0 * c4[dy].z + a1 * c4[dy].w + a2 * n4[dy].x;
                    lft[dy] = c4[dy].w; c4[dy] = n4[dy];
                }
                ssqacc += o0 * o0 + o1 * o1 + o2 * o2 + o3 * o3;
                unsigned short hb0 = f2bf(o0), hb1 = f2bf(o1), hb2 = f2bf(o2), hb3 = f2bf(o3);
                short4v hv = {(short)hb0, (short)hb1, (short)hb2, (short)hb3};
                short4v lv = {(short)f2bf(o0 - bf2f(hb0)), (short)f2bf(o1 - bf2f(hb1)),
                              (short)f2bf(o2 - bf2f(hb2)), (short)f2bf(o3 - bf2f(hb3))};
                *(short4v*)&sm.tiles[qk * 2][c][xb] = hv;
                *(short4v*)&sm.tiles[qk * 2 + 1][c][xb] = lv;
            }
        }
        __syncthreads();
        // Gram via MFMA on this row, wave handles px [px0, px0+32)
        bf16x8 qh[3], ql_[3], kh[3], kl[3];
#pragma unroll
        for (int i = 0; i < 3; ++i) {
            qh[i]  = *(const bf16x8*)&sm.tiles[0][i * 16 + l15][px0 + quad * 8];
            ql_[i] = *(const bf16x8*)&sm.tiles[1][i * 16 + l15][px0 + quad * 8];
            kh[i]  = *(const bf16x8*)&sm.tiles[2][i * 16 + l15][px0 + quad * 8];
            kl[i]  = *(const bf16x8*)&sm.tiles[3][i * 16 + l15][px0 + quad * 8];
        }
#pragma unroll
        for (int ci = 0; ci < 3; ++ci)
#pragma unroll
            for (int di = 0; di < 3; ++di) {
                acc[ci][di] = __builtin_amdgcn_mfma_f32_16x16x32_bf16(qh[ci],  kh[di], acc[ci][di], 0, 0, 0);
                acc[ci][di] = __builtin_amdgcn_mfma_f32_16x16x32_bf16(qh[ci],  kl[di], acc[ci][di], 0, 0, 0);
                acc[ci][di] = __builtin_amdgcn_mfma_f32_16x16x32_bf16(ql_[ci], kh[di], acc[ci][di], 0, 0, 0);
            }
        __syncthreads();
    }

    // per-wave partials -> LDS -> one atomicAdd set per block
#pragma unroll
    for (int ci = 0; ci < 3; ++ci)
#pragma unroll
        for (int di = 0; di < 3; ++di)
#pragma unroll
            for (int r = 0; r < 4; ++r) {
                int cc = ci * 16 + quad * 4 + r;
                int dd = di * 16 + l15;
                sm.sred[wid * 2304 + cc * 48 + dd] = acc[ci][di][r];
            }
    __syncthreads();
    {
        float* Sbh = Sg + (size_t)(b * NH + h) * 2304;
#pragma unroll
        for (int i = 0; i < 9; ++i) {
            int e = t * 9 + i;
            float s = sm.sred[e] + sm.sred[2304 + e] + sm.sred[4608 + e] + sm.sred[6912 + e];
            atomicAdd(&Sbh[e], s);
        }
    }
    if (t < 192) atomicAdd(&ssqg[((b * NH + h) * 2 + qk) * 48 + c], ssqacc);
}

// ---------------------------------------------------------------------------
// Kernel 2: per attn row: normalize, rank, 4 nested-topk softmaxes -> M
// one wave per row (b,h,c); grid 192 x 256
// ---------------------------------------------------------------------------
__global__ void k_attn(const float* __restrict__ Sg, const float* __restrict__ ssqg,
                       const float* __restrict__ temp, const float* __restrict__ aw,
                       float* __restrict__ Mg)
{
    const int t = threadIdx.x;
    const int r = blockIdx.x * 4 + (t >> 6);   // 0..767
    const int lane = t & 63;
    const int c = r % 48, h = (r / 48) % NH, b = r / (48 * NH);
    const float* Srow = Sg + ((size_t)(b * NH + h) * 48 + c) * 48;
    const float* sq = ssqg + (size_t)(b * NH + h) * 96;

    float v = -3.0e38f;
    if (lane < 48) {
        float nq = fmaxf(sqrtf(sq[c]), 1e-12f);
        float nk = fmaxf(sqrtf(sq[48 + lane]), 1e-12f);
        v = Srow[lane] / (nq * nk) * temp[h];
    }
    float m = v;
#pragma unroll
    for (int off = 32; off; off >>= 1) m = fmaxf(m, __shfl_xor(m, off));
    int rank = 0;
    for (int e = 0; e < 48; ++e) {
        float ve = __shfl(v, e);
        rank += ((ve > v) || (ve == v && e < lane)) ? 1 : 0;
    }
    float ed = (lane < 48) ? __expf(v - m) : 0.f;
    const int K4[4] = {24, 32, 36, 38};
    float f = 0.f;
#pragma unroll
    for (int i = 0; i < 4; ++i) {
        float x = (rank < K4[i]) ? ed : 0.f;
#pragma unroll
        for (int off = 32; off; off >>= 1) x += __shfl_xor(x, off);
        if (rank < K4[i]) f += aw[i] / x;
    }
    if (lane < 48) Mg[((size_t)(b * NH + h) * 48 + c) * 48 + lane] = ed * f;
}

// ---------------------------------------------------------------------------
// Kernel 3: W2[b][co][gd] = sum_c Wproj[co][h*48+c] * M[b,h][c][d]  -> bf16
// ---------------------------------------------------------------------------
__global__ void k_w2(const float* __restrict__ wproj, const float* __restrict__ Mg,
                     unsigned short* __restrict__ W2)
{
    int idx = blockIdx.x * 256 + threadIdx.x;    // < 2*384*384
    int gd = idx % 384; int co = (idx / 384) % 384; int b = idx / (384 * 384);
    int h = gd / 48, d = gd % 48;
    const float* wp = wproj + (size_t)co * 384 + h * 48;
    const float* Mp = Mg + (size_t)(b * NH + h) * 2304 + d;
    float s = 0.f;
#pragma unroll
    for (int cc = 0; cc < 48; ++cc) s += wp[cc] * Mp[cc * 48];
    W2[idx] = f2bf(s);
}

// ---------------------------------------------------------------------------
// Kernel 4: Vconv = dwconv3x3(v_fea) -> bf16 [b][ch][hw]; one block per (b,ch)
// ---------------------------------------------------------------------------
__global__ __launch_bounds__(256) void k_vconv(const float* __restrict__ vf,
                                               const float* __restrict__ wv,
                                               unsigned short* __restrict__ Vc)
{
    const int bc = blockIdx.x;          // b*384+ch
    const int ch = bc % CH;
    const float* plane = vf + (size_t)bc * HW;
    const float* wp = wv + ch * 9;
    float w9[9];
#pragma unroll
    for (int i = 0; i < 9; ++i) w9[i] = wp[i];
    const int t = threadIdx.x;
    const int y = t >> 1, x0 = (t & 1) * 64;
    unsigned short* op = Vc + (size_t)bc * HW + y * IMG;

    float lft[3]; float4 c4[3];
    const float* rp[3]; bool rv[3];
#pragma unroll
    for (int dy = 0; dy < 3; ++dy) {
        int yy = y + dy - 1;
        rv[dy] = (yy >= 0 && yy < IMG);
        rp[dy] = plane + yy * IMG;
        lft[dy] = (rv[dy] && x0 > 0) ? rp[dy][x0 - 1] : 0.f;
        c4[dy] = rv[dy] ? *(const float4*)(rp[dy] + x0) : make_float4(0, 0, 0, 0);
    }
#pragma unroll
    for (int j = 0; j < 16; ++j) {
        const int xb = x0 + 4 * j;
        float4 n4[3];
#pragma unroll
        for (int dy = 0; dy < 3; ++dy) {
            if (j < 15)
                n4[dy] = rv[dy] ? *(const float4*)(rp[dy] + xb + 4) : make_float4(0, 0, 0, 0);
            else {
                float tl = (rv[dy] && (x0 + 64) < IMG) ? rp[dy][x0 + 64] : 0.f;
                n4[dy] = make_float4(tl, 0, 0, 0);
            }
        }
        float o0 = 0, o1 = 0, o2 = 0, o3 = 0;
#pragma unroll
        for (int dy = 0; dy < 3; ++dy) {
            float a0 = w9[dy * 3], a1 = w9[dy * 3 + 1], a2 = w9[dy * 3 + 2];
            o0 += a0 * lft[dy]  + a1 * c4[dy].x + a2 * c4[dy].y;
            o1 += a0 * c4[dy].x + a1 * c4[dy].y + a2 * c4[dy].z;
            o2 += a0 * c4[dy].y + a1 * c4[dy].z + a2 * c4[dy].w;
            o3 += a0 * c4[dy].z + a1 * c4[dy].w + a2 * n4[dy].x;
            lft[dy] = c4[dy].w; c4[dy] = n4[dy];
        }
        short4v pv = {(short)f2bf(o0), (short)f2bf(o1), (short)f2bf(o2), (short)f2bf(o3)};
        *(short4v*)&op[xb] = pv;
    }
}

// ---------------------------------------------------------------------------
// Kernel 5: out[b] = W2[b] (384x384 bf16) @ Vconv[b] (384x16384 bf16), fp32 out
// grid (128 y-tiles, 3 m-tiles, 2 batch), block 256 = 4 waves of 64x64
// ---------------------------------------------------------------------------
__global__ __launch_bounds__(256) void k_gemm(const unsigned short* __restrict__ W2,
        const unsigned short* __restrict__ Vc,
        const float* __restrict__ vf, const float* __restrict__ wv,
        float* __restrict__ out, int staged)
{
    __shared__ unsigned short Ab[128][40];
    __shared__ unsigned short Bb[128][40];
    const int t = threadIdx.x;
    const int y = blockIdx.x, mt = blockIdx.y, b = blockIdx.z;
    const int wid = t >> 6, lane = t & 63, quad = lane >> 4, l15 = lane & 15;
    const int wm = wid >> 1, wn = wid & 1;

    f32x4 acc[4][4];
#pragma unroll
    for (int i = 0; i < 4; ++i)
#pragma unroll
        for (int j = 0; j < 4; ++j) acc[i][j] = (f32x4){0.f, 0.f, 0.f, 0.f};

    for (int kt = 0; kt < 12; ++kt) {
        const int K0 = kt * 32;
#pragma unroll
        for (int j = 0; j < 2; ++j) {
            int cid = t + 256 * j; int row = cid >> 2, k8 = cid & 3;
            bf16x8 vv = *(const bf16x8*)(W2 + ((size_t)(b * CH + mt * 128 + row) * CH + K0 + k8 * 8));
            *(bf16x8*)&Ab[row][k8 * 8] = vv;
        }
        if (staged) {
#pragma unroll
            for (int j = 0; j < 2; ++j) {
                int cid = t + 256 * j; int k = cid >> 4, x8 = cid & 15;
                bf16x8 vv = *(const bf16x8*)(Vc + ((size_t)(b * CH + K0 + k) * HW + y * IMG + x8 * 8));
#pragma unroll
                for (int i = 0; i < 8; ++i) Bb[x8 * 8 + i][k] = (unsigned short)vv[i];
            }
        } else {
            for (int j = 0; j < 2; ++j) {
                int cid = t + 256 * j; int k = cid >> 4, x8 = cid & 15;
                int gc = K0 + k;
                const float* plane = vf + (size_t)(b * CH + gc) * HW;
                const float* wp = wv + gc * 9;
                for (int i = 0; i < 8; ++i) {
                    int x = x8 * 8 + i; float s = 0.f;
                    for (int ky = 0; ky < 3; ++ky) {
                        int yy = y + ky - 1; if (yy < 0 || yy >= IMG) continue;
                        const float* rp = plane + yy * IMG;
                        for (int kx = 0; kx < 3; ++kx) {
                            int xx = x + kx - 1; if (xx < 0 || xx >= IMG) continue;
                            s += rp[xx] * wp[ky * 3 + kx];
                        }
                    }
                    Bb[x][k] = f2bf(s);
                }
            }
        }
        __syncthreads();
        bf16x8 af[4], bfr[4];
#pragma unroll
        for (int i = 0; i < 4; ++i) af[i]  = *(const bf16x8*)&Ab[wm * 64 + i * 16 + l15][quad * 8];
#pragma unroll
        for (int i = 0; i < 4; ++i) bfr[i] = *(const bf16x8*)&Bb[wn * 64 + i * 16 + l15][quad * 8];
#pragma unroll
        for (int mi = 0; mi < 4; ++mi)
#pragma unroll
            for (int ni = 0; ni < 4; ++ni)
                acc[mi][ni] = __builtin_amdgcn_mfma_f32_16x16x32_bf16(af[mi], bfr[ni], acc[mi][ni], 0, 0, 0);
        __syncthreads();
    }
#pragma unroll
    for (int mi = 0; mi < 4; ++mi)
#pragma unroll
        for (int ni = 0; ni < 4; ++ni)
#pragma unroll
            for (int r = 0; r < 4; ++r) {
                int co = mt * 128 + wm * 64 + mi * 16 + quad * 4 + r;
                int n  = y * IMG + wn * 64 + ni * 16 + l15;
                out[(size_t)(b * CH + co) * HW + n] = acc[mi][ni][r];
            }
}

// ---------------------------------------------------------------------------
extern "C" void kernel_launch(void* const* d_in, const int* in_sizes, int n_in,
                              void* d_out, int out_size, void* d_ws, size_t ws_size,
                              hipStream_t stream)
{
    const float* k_fea = (const float*)d_in[0];
    const float* v_fea = (const float*)d_in[1];
    const float* q_fea = (const float*)d_in[2];
    const float* wq = (const float*)d_in[3];
    const float* wk = (const float*)d_in[4];
    const float* wv = (const float*)d_in[5];
    const float* wproj = (const float*)d_in[6];
    const float* temp = (const float*)d_in[7];
    const float* aw = (const float*)d_in[8];
    float* out = (float*)d_out;

    char* ws = (char*)d_ws;
    float* Sg   = (float*)ws;                              // 36864 f32
    float* ssqg = (float*)(ws + 36864 * 4);                // 1536 f32
    float* Mg   = (float*)(ws + 153600);                   // 36864 f32
    unsigned short* W2 = (unsigned short*)(ws + 301056);   // 294912 bf16
    unsigned short* Vc = (unsigned short*)(ws + 890880);   // 12582912 bf16
    const size_t need = 890880 + (size_t)12582912 * 2;
    const int staged = (ws_size >= need) ? 1 : 0;

    hipMemsetAsync(d_ws, 0, 153600, stream);  // zero Sg + ssqg
    k_gram<<<dim3(32, 8, 2), 256, 0, stream>>>(q_fea, k_fea, wq, wk, Sg, ssqg);
    k_attn<<<192, 256, 0, stream>>>(Sg, ssqg, temp, aw, Mg);
    k_w2<<<1152, 256, 0, stream>>>(wproj, Mg, W2);
    if (staged) k_vconv<<<768, 256, 0, stream>>>(v_fea, wv, Vc);
    k_gemm<<<dim3(128, 3, 2), 256, 0, stream>>>(W2, Vc, v_fea, wv, out, staged);
}